// Round 1
// baseline (1448.073 us; speedup 1.0000x reference)
//
#include <hip/hip_runtime.h>
#include <math.h>

#define NEGV (-1e30f)
#define STAR_PEN (-1.0f)

#if __has_builtin(__builtin_amdgcn_exp2f)
#define EXP2(x) __builtin_amdgcn_exp2f(x)
#else
#define EXP2(x) exp2f(x)
#endif
#if __has_builtin(__builtin_amdgcn_logf)
#define LOG2(x) __builtin_amdgcn_logf(x)
#else
#define LOG2(x) log2f(x)
#endif

#define LOG2E 1.4426950408889634f
#define LN2   0.6931471805599453f

// ---------------------------------------------------------------------------
// Kernel 1: logits = feat @ W^T + b, then log_softmax per row -> logp (fp32)
// Tile: 64 rows x V(<=64) cols per block, 256 threads, 4x4 register acc.
// LDS strides of 36 floats keep ds_read_b128 16B-aligned with <=2-way bank
// aliasing (free). Epilogue computes row-wise logsumexp through LDS.
// ---------------------------------------------------------------------------
__global__ __launch_bounds__(256) void gemm_logsoftmax(
    const float* __restrict__ feat, const float* __restrict__ W,
    const float* __restrict__ bias, float* __restrict__ logp,
    int nrows, int D, int V)
{
  __shared__ float smem[4320];        // fT[64*36] | wT[56*36]; reused as ltile[64*57]+lse
  float* fT = smem;
  float* wT = smem + 64 * 36;

  const int tid = threadIdx.x;
  const int rg = tid & 15;            // row group: rows rg + 16*i
  const int cg = tid >> 4;            // col group: cols cg*4 + j
  const int row0 = blockIdx.x * 64;
  const bool active = (cg * 4 < V);

  float acc[4][4];
  #pragma unroll
  for (int i = 0; i < 4; ++i)
    #pragma unroll
    for (int j = 0; j < 4; ++j) acc[i][j] = 0.f;

  const int nf4 = 64 * 8;
  const int nw4 = V * 8;

  for (int d0 = 0; d0 < D; d0 += 32) {
    for (int idx = tid; idx < nf4; idx += 256) {
      int r = idx >> 3, kk = idx & 7;
      int row = row0 + r;
      float4 v = make_float4(0.f, 0.f, 0.f, 0.f);
      if (row < nrows) v = *(const float4*)(feat + (size_t)row * D + d0 + kk * 4);
      *(float4*)(fT + r * 36 + kk * 4) = v;
    }
    for (int idx = tid; idx < nw4; idx += 256) {
      int c = idx >> 3, kk = idx & 7;
      float4 v = *(const float4*)(W + (size_t)c * D + d0 + kk * 4);
      *(float4*)(wT + c * 36 + kk * 4) = v;
    }
    __syncthreads();
    if (active) {
      #pragma unroll
      for (int kk = 0; kk < 8; ++kk) {
        float4 a[4], w[4];
        #pragma unroll
        for (int i = 0; i < 4; ++i) a[i] = *(float4*)(fT + (rg + 16 * i) * 36 + kk * 4);
        #pragma unroll
        for (int j = 0; j < 4; ++j) w[j] = *(float4*)(wT + (cg * 4 + j) * 36 + kk * 4);
        #pragma unroll
        for (int i = 0; i < 4; ++i)
          #pragma unroll
          for (int j = 0; j < 4; ++j)
            acc[i][j] += a[i].x * w[j].x + a[i].y * w[j].y +
                         a[i].z * w[j].z + a[i].w * w[j].w;
      }
    }
    __syncthreads();
  }

  // epilogue: log-softmax per row
  float bj[4] = {0.f, 0.f, 0.f, 0.f};
  if (active) {
    #pragma unroll
    for (int j = 0; j < 4; ++j) bj[j] = bias[cg * 4 + j];
  }
  float* ltile = smem;                // [64][57]
  float* lse = smem + 64 * 57;        // [64]
  if (active) {
    #pragma unroll
    for (int i = 0; i < 4; ++i)
      #pragma unroll
      for (int j = 0; j < 4; ++j)
        ltile[(rg + 16 * i) * 57 + cg * 4 + j] = acc[i][j] + bj[j];
  }
  __syncthreads();
  if (tid < 64) {
    const float* rowp = ltile + tid * 57;
    float m = -INFINITY;
    for (int c = 0; c < V; ++c) m = fmaxf(m, rowp[c]);
    float s = 0.f;
    for (int c = 0; c < V; ++c) s += EXP2((rowp[c] - m) * LOG2E);
    lse[tid] = m + LOG2(s) * LN2;
  }
  __syncthreads();
  if (active) {
    #pragma unroll
    for (int i = 0; i < 4; ++i) {
      int row = row0 + rg + 16 * i;
      if (row < nrows) {
        float l = lse[rg + 16 * i];
        float4 o;
        o.x = acc[i][0] + bj[0] - l;
        o.y = acc[i][1] + bj[1] - l;
        o.z = acc[i][2] + bj[2] - l;
        o.w = acc[i][3] + bj[3] - l;
        *(float4*)(logp + (size_t)row * V + cg * 4) = o;
      }
    }
  }
}

// ---------------------------------------------------------------------------
// Kernel 2: Star-CTC DP. One block per sequence; 1 state/thread; ping-pong
// alpha in LDS; double-buffered prefetch of the logp row; 1 barrier/step.
// ---------------------------------------------------------------------------
__global__ __launch_bounds__(576, 1) void star_ctc_dp(
    const float* __restrict__ logp, const int* __restrict__ targets,
    const int* __restrict__ in_len, const int* __restrict__ tgt_len,
    float* __restrict__ partial, int T, int S, int V)
{
  extern __shared__ float sh[];
  const int L = 2 * S + 1;
  float* alpha = sh;                  // [2][L]
  float* prow = sh + 2 * L;           // [2][64]

  const int n = blockIdx.x;
  const int l = threadIdx.x;
  const int len = in_len[n];
  const int tl = tgt_len[n];
  const float* lp = logp + (size_t)n * T * V;

  const bool valid = (l < L);
  const bool is_star = ((l & 1) == 0);
  int label = 0;
  bool skip_ok = false;
  if (valid && !is_star) {
    label = targets[n * S + ((l - 1) >> 1)];
    if (l >= 3) skip_ok = (label != targets[n * S + ((l - 3) >> 1)]);
  }

  // t = 0
  if (l < V) prow[l] = lp[l];
  __syncthreads();
  float a = NEGV;
  if (valid && l < 2) a = is_star ? STAR_PEN : prow[label];
  if (valid) alpha[l] = a;
  if (l < V && 1 < len) prow[64 + l] = lp[V + l];
  __syncthreads();

  for (int t = 1; t < len; ++t) {
    const int cur = t & 1, prv = cur ^ 1;
    float nv = a;
    if (valid) {
      float a1 = (l >= 1) ? alpha[prv * L + l - 1] : NEGV;
      float a2 = skip_ok ? alpha[prv * L + l - 2] : NEGV;
      float m = fmaxf(a, fmaxf(a1, a2));
      float s = EXP2((a - m) * LOG2E) + EXP2((a1 - m) * LOG2E) +
                EXP2((a2 - m) * LOG2E);
      float e = is_star ? STAR_PEN : prow[cur * 64 + label];
      nv = m + LOG2(s) * LN2 + e;
      a = nv;
    }
    if (l < V && t + 1 < len) prow[((t + 1) & 1) * 64 + l] = lp[(size_t)(t + 1) * V + l];
    if (valid) alpha[cur * L + l] = nv;
    __syncthreads();
  }

  if (l == 0) {
    const int fb = (len - 1) & 1;
    const int last = 2 * tl;
    float x = alpha[fb * L + last];
    float y = alpha[fb * L + last - 1];
    float m = fmaxf(x, y);
    float s = EXP2((x - m) * LOG2E) + EXP2((y - m) * LOG2E);
    float score = m + LOG2(s) * LN2;
    partial[n] = -score / (float)tl;
  }
}

// ---------------------------------------------------------------------------
// Kernel 3: mean over batch
// ---------------------------------------------------------------------------
__global__ void reduce_mean(const float* __restrict__ partial,
                            float* __restrict__ out, int B)
{
  float v = 0.f;
  for (int i = threadIdx.x; i < B; i += 64) v += partial[i];
  #pragma unroll
  for (int off = 32; off > 0; off >>= 1) v += __shfl_down(v, off, 64);
  if (threadIdx.x == 0) out[0] = v / (float)B;
}

extern "C" void kernel_launch(void* const* d_in, const int* in_sizes, int n_in,
                              void* d_out, int out_size, void* d_ws, size_t ws_size,
                              hipStream_t stream)
{
  const float* feat = (const float*)d_in[0];
  const float* W = (const float*)d_in[1];
  const float* bias = (const float*)d_in[2];
  const int* targets = (const int*)d_in[3];
  const int* in_len = (const int*)d_in[4];
  const int* tgt_len = (const int*)d_in[5];
  float* out = (float*)d_out;

  const int V = in_sizes[2];
  const int D = in_sizes[1] / V;
  const int B = in_sizes[4];
  const int T = in_sizes[0] / (B * D);
  const int S = in_sizes[3] / B;
  const int nrows = B * T;

  float* logp = (float*)d_ws;                       // nrows * V floats
  float* partial = logp + (size_t)nrows * V;        // B floats

  dim3 g1((nrows + 63) / 64);
  gemm_logsoftmax<<<g1, 256, 0, stream>>>(feat, W, bias, logp, nrows, D, V);

  const int L = 2 * S + 1;
  const int threads = ((L + 63) / 64) * 64;         // 576 for S=256
  const size_t shmem = (2 * (size_t)L + 2 * 64) * sizeof(float);
  star_ctc_dp<<<B, threads, shmem, stream>>>(logp, targets, in_len, tgt_len,
                                             partial, T, S, V);

  reduce_mean<<<1, 64, 0, stream>>>(partial, out, B);
}

// Round 4
// 920.226 us; speedup vs baseline: 1.5736x; 1.5736x over previous
//
#include <hip/hip_runtime.h>
#include <math.h>

typedef __attribute__((ext_vector_type(4))) float f32x4;
typedef __attribute__((ext_vector_type(8))) short s16x8;

#define LOG2E 1.4426950408889634f
#define LN2f  0.6931471805599453f
#define INV_E 0.36787944117144233f

__device__ __forceinline__ short bfc(float x) {
  unsigned u = __float_as_uint(x);
  unsigned r = u + 0x7fffu + ((u >> 16) & 1u);   // RNE to bf16
  return (short)(r >> 16);
}

__device__ __forceinline__ float bperm(float v, int byte_addr) {
  return __int_as_float(__builtin_amdgcn_ds_bpermute(byte_addr, __float_as_int(v)));
}

__device__ __forceinline__ float rdlane(float v, int lane) {
  return __int_as_float(__builtin_amdgcn_readlane(__float_as_int(v), lane));
}

// ---------------------------------------------------------------------------
// Kernel 0: W (V x D fp32) -> Wb (64 x D bf16), rows >= V zero-filled.
// ---------------------------------------------------------------------------
__global__ void conv_w(const float* __restrict__ W, short* __restrict__ Wb,
                       int V, int D) {
  int idx = blockIdx.x * blockDim.x + threadIdx.x;
  if (idx >= 64 * D) return;
  int row = idx / D, col = idx - row * D;
  Wb[idx] = (row < V) ? bfc(W[(size_t)row * D + col]) : (short)0;
}

// ---------------------------------------------------------------------------
// Kernel 1: per row: logits = feat @ W^T + b; m = rowmax; p~ = exp(logit-m)
// -> pt[row][0..55]; pt[row][56] = K = ln(sum p~); pt[row][57] = star~ =
// sum * e^-1; cols 58..63 = 0. bf16 MFMA 16x16x32, 16 rows/wave, no LDS.
// ---------------------------------------------------------------------------
__global__ __launch_bounds__(256) void gemm_pexp(
    const float* __restrict__ feat, const short* __restrict__ Wb,
    const float* __restrict__ bias, float* __restrict__ pt,
    int nrows, int D, int V) {
  const int lane = threadIdx.x & 63;
  const int wave = threadIdx.x >> 6;
  const int m_lo = lane & 15;
  const int q = lane >> 4;
  const int rowbase = (blockIdx.x * 4 + wave) * 16;

  int arow = rowbase + m_lo;
  if (arow >= nrows) arow = nrows - 1;           // clamp loads; stores guarded
  const float* Ap = feat + (size_t)arow * D + q * 8;
  const short* Bp = Wb + (size_t)m_lo * D + q * 8;
  const size_t bstr = (size_t)16 * D;

  f32x4 acc[4];
  #pragma unroll
  for (int ni = 0; ni < 4; ++ni) acc[ni] = (f32x4){0.f, 0.f, 0.f, 0.f};

  float4 al = *(const float4*)(Ap);
  float4 ah = *(const float4*)(Ap + 4);
  s16x8 b0 = *(const s16x8*)(Bp);
  s16x8 b1 = *(const s16x8*)(Bp + bstr);
  s16x8 b2 = *(const s16x8*)(Bp + 2 * bstr);
  s16x8 b3 = *(const s16x8*)(Bp + 3 * bstr);

  for (int k0 = 0; k0 < D; k0 += 32) {
    const int kn = (k0 + 32 < D) ? (k0 + 32) : 0;  // dummy reload on last iter
    const float* Apn = feat + (size_t)arow * D + kn + q * 8;
    const short* Bpn = Wb + (size_t)m_lo * D + kn + q * 8;
    float4 nal = *(const float4*)(Apn);
    float4 nah = *(const float4*)(Apn + 4);
    s16x8 nb0 = *(const s16x8*)(Bpn);
    s16x8 nb1 = *(const s16x8*)(Bpn + bstr);
    s16x8 nb2 = *(const s16x8*)(Bpn + 2 * bstr);
    s16x8 nb3 = *(const s16x8*)(Bpn + 3 * bstr);

    s16x8 av;
    av[0] = bfc(al.x); av[1] = bfc(al.y); av[2] = bfc(al.z); av[3] = bfc(al.w);
    av[4] = bfc(ah.x); av[5] = bfc(ah.y); av[6] = bfc(ah.z); av[7] = bfc(ah.w);

    acc[0] = __builtin_amdgcn_mfma_f32_16x16x32_bf16(av, b0, acc[0], 0, 0, 0);
    acc[1] = __builtin_amdgcn_mfma_f32_16x16x32_bf16(av, b1, acc[1], 0, 0, 0);
    acc[2] = __builtin_amdgcn_mfma_f32_16x16x32_bf16(av, b2, acc[2], 0, 0, 0);
    acc[3] = __builtin_amdgcn_mfma_f32_16x16x32_bf16(av, b3, acc[3], 0, 0, 0);

    al = nal; ah = nah; b0 = nb0; b1 = nb1; b2 = nb2; b3 = nb3;
  }

  float bias_v[4];
  #pragma unroll
  for (int ni = 0; ni < 4; ++ni) {
    int col = ni * 16 + m_lo;
    bias_v[ni] = (col < V) ? bias[col] : 0.f;
  }

  // C/D layout: col = lane&15, row = (lane>>4)*4 + reg   [m89-verified]
  #pragma unroll
  for (int r = 0; r < 4; ++r) {
    int grow = rowbase + q * 4 + r;
    float lg[4];
    #pragma unroll
    for (int ni = 0; ni < 4; ++ni) {
      int col = ni * 16 + m_lo;
      lg[ni] = (col < V) ? (acc[ni][r] + bias_v[ni]) : -1e30f;
    }
    float m = fmaxf(fmaxf(lg[0], lg[1]), fmaxf(lg[2], lg[3]));
    #pragma unroll
    for (int off = 1; off < 16; off <<= 1) m = fmaxf(m, __shfl_xor(m, off));
    float p[4];
    #pragma unroll
    for (int ni = 0; ni < 4; ++ni) p[ni] = exp2f((lg[ni] - m) * LOG2E);
    float s = (p[0] + p[1]) + (p[2] + p[3]);
    #pragma unroll
    for (int off = 1; off < 16; off <<= 1) s += __shfl_xor(s, off);

    if (grow < nrows) {
      float* orow = pt + (size_t)grow * 64;
      orow[m_lo] = p[0];
      orow[16 + m_lo] = p[1];
      orow[32 + m_lo] = p[2];
      if (m_lo < 8)       orow[48 + m_lo] = p[3];
      else if (m_lo == 8) orow[56] = logf(s);        // K_t (ln units)
      else if (m_lo == 9) orow[57] = s * INV_E;      // star~ emission
      else                orow[48 + m_lo] = 0.f;     // cols 58..63
    }
  }
}

// ---------------------------------------------------------------------------
// Kernel 2: Star-CTC DP, linear domain, per-lane block-floating-point with
// FRAME-RAISE merging. Lane k holds states 8k..8k+7 (+ shadow 8k+8), true
// alpha = a * 2^eps(lane). Incoming left value l7 (state 8k-1, frame eL):
// if eL > eps, raise own frame to eL (scale self DOWN — never scale the
// incoming up, so no overflow is possible); else scale incoming down.
// Skip source for state 8k+1 is state 8k-1 == l7 (r2/r3 used l6 - bug).
// No barriers, no transcendentals in the loop.
// ---------------------------------------------------------------------------
__global__ __launch_bounds__(64) void star_dp(
    const float* __restrict__ pt, const int* __restrict__ targets,
    const int* __restrict__ in_len, const int* __restrict__ tgt_len,
    float* __restrict__ partial, int T, int S) {
  const int n = blockIdx.x;
  const int lane = threadIdx.x;
  const float* row = pt + (size_t)n * T * 64;
  const int len = in_len[n];
  const int tl = tgt_len[n];
  const int* tg = targets + (size_t)n * S;

  const int s0 = lane * 4;
  int lab1 = (s0     < S) ? tg[s0]     : 0;
  int lab3 = (s0 + 1 < S) ? tg[s0 + 1] : 0;
  int lab5 = (s0 + 2 < S) ? tg[s0 + 2] : 0;
  int lab7 = (s0 + 3 < S) ? tg[s0 + 3] : 0;
  int labL = __shfl_up(lab7, 1);                 // label of state 8k-1
  const bool sk1 = (lane > 0) && (lab1 != labL);
  const bool sk3 = (lab3 != lab1);
  const bool sk5 = (lab5 != lab3);
  const bool sk7 = (lab7 != lab5);
  const int ad1 = lab1 << 2, ad3 = lab3 << 2, ad5 = lab5 << 2, ad7 = lab7 << 2;

  float a0 = 0, a1 = 0, a2 = 0, a3 = 0, a4 = 0, a5 = 0, a6 = 0, a7 = 0, a8 = 0;
  int eps = 0;
  bool act = (lane == 0);

  float rc = row[lane];
  float r1 = row[(size_t)((len > 1) ? 1 : 0) * 64 + lane];
  float r2 = row[(size_t)((len > 2) ? 2 : (len - 1)) * 64 + lane];

  { // t = 0
    float star = rdlane(rc, 57);
    float e1 = bperm(rc, ad1);
    if (lane == 0) { a0 = star; a1 = e1; }
  }
  float ksum = rc;              // lane 56 accumulates Sum K_t
  float l7 = 0.f;
  int eL = 0;

  for (int t = 1; t < len; ++t) {
    float cur = r1; r1 = r2;
    int tn = (t + 2 < len) ? (t + 2) : (len - 1);
    r2 = row[(size_t)tn * 64 + lane];

    if (!act) eps = eL;                         // zeros valid in any frame
    const bool inc = (lane != 0) && (l7 != 0.f);
    int d = inc ? (eL - eps) : 0;
    int up = (d > 0) ? d : 0;                   // frame raise (scale self DOWN)
    a0 = ldexpf(a0, -up); a1 = ldexpf(a1, -up); a2 = ldexpf(a2, -up);
    a3 = ldexpf(a3, -up); a4 = ldexpf(a4, -up); a5 = ldexpf(a5, -up);
    a6 = ldexpf(a6, -up); a7 = ldexpf(a7, -up); a8 = ldexpf(a8, -up);
    eps += up;
    float l7s = inc ? ldexpf(l7, d - up) : 0.f; // shift <= 0: never overflows
    act = act || (l7s != 0.f);

    float star = rdlane(cur, 57);
    float e1 = bperm(cur, ad1);
    float e3 = bperm(cur, ad3);
    float e5 = bperm(cur, ad5);
    float e7 = bperm(cur, ad7);

    float n0 = (a0 + l7s) * star;
    float n1 = (a1 + a0 + (sk1 ? l7s : 0.f)) * e1;   // skip src = state 8k-1
    float n2 = (a2 + a1) * star;
    float n3 = (a3 + a2 + (sk3 ? a1 : 0.f)) * e3;
    float n4 = (a4 + a3) * star;
    float n5 = (a5 + a4 + (sk5 ? a3 : 0.f)) * e5;
    float n6 = (a6 + a5) * star;
    float n7 = (a7 + a6 + (sk7 ? a5 : 0.f)) * e7;
    float n8 = (a8 + a7) * star;
    a0 = n0; a1 = n1; a2 = n2; a3 = n3; a4 = n4;
    a5 = n5; a6 = n6; a7 = n7; a8 = n8;

    ksum += cur;

    if ((t & 7) == 0) {                        // per-lane renorm to [0.5, 1)
      float m = fmaxf(fmaxf(fmaxf(a0, a1), fmaxf(a2, a3)),
                      fmaxf(fmaxf(a4, a5), fmaxf(a6, a7)));
      m = fmaxf(m, a8);
      int e = (int)((__float_as_uint(m) >> 23) & 255) - 126;
      e = (act && m > 0.f) ? e : 0;
      a0 = ldexpf(a0, -e); a1 = ldexpf(a1, -e); a2 = ldexpf(a2, -e);
      a3 = ldexpf(a3, -e); a4 = ldexpf(a4, -e); a5 = ldexpf(a5, -e);
      a6 = ldexpf(a6, -e); a7 = ldexpf(a7, -e); a8 = ldexpf(a8, -e);
      eps += e;
    }

    l7 = __shfl_up(a7, 1);                     // state 8k-1 for next step
    eL = __shfl_up(eps, 1);
  }

  __shared__ float sh[64 * 9];
  __shared__ int she[64];
  sh[lane * 9 + 0] = a0; sh[lane * 9 + 1] = a1; sh[lane * 9 + 2] = a2;
  sh[lane * 9 + 3] = a3; sh[lane * 9 + 4] = a4; sh[lane * 9 + 5] = a5;
  sh[lane * 9 + 6] = a6; sh[lane * 9 + 7] = a7; sh[lane * 9 + 8] = a8;
  she[lane] = eps;
  float k56 = __shfl(ksum, 56);
  __syncthreads();
  if (lane == 0) {
    int last = 2 * tl;
    int kx = last >> 3, jx = last & 7;
    if (kx > 63) { kx = 63; jx = last - 504; }     // state 512 -> lane63 a8
    int ky = (last - 1) >> 3, jy = (last - 1) & 7;
    float sx = sh[kx * 9 + jx]; int ex = she[kx];
    float sy = sh[ky * 9 + jy]; int ey = she[ky];
    int em = (ex > ey) ? ex : ey;
    float v = ldexpf(sx, ex - em) + ldexpf(sy, ey - em);
    float score = logf(v) + (float)em * LN2f - k56;
    partial[n] = -score / (float)tl;
  }
}

// ---------------------------------------------------------------------------
// Kernel 3: mean over batch
// ---------------------------------------------------------------------------
__global__ void reduce_mean(const float* __restrict__ partial,
                            float* __restrict__ out, int B) {
  float v = 0.f;
  for (int i = threadIdx.x; i < B; i += 64) v += partial[i];
  #pragma unroll
  for (int off = 32; off > 0; off >>= 1) v += __shfl_down(v, off, 64);
  if (threadIdx.x == 0) out[0] = v / (float)B;
}

extern "C" void kernel_launch(void* const* d_in, const int* in_sizes, int n_in,
                              void* d_out, int out_size, void* d_ws, size_t ws_size,
                              hipStream_t stream) {
  const float* feat = (const float*)d_in[0];
  const float* W = (const float*)d_in[1];
  const float* bias = (const float*)d_in[2];
  const int* targets = (const int*)d_in[3];
  const int* in_len = (const int*)d_in[4];
  const int* tgt_len = (const int*)d_in[5];
  float* out = (float*)d_out;

  const int V = in_sizes[2];
  const int D = in_sizes[1] / V;
  const int B = in_sizes[4];
  const int T = in_sizes[0] / (B * D);
  const int S = in_sizes[3] / B;
  const int nrows = B * T;

  float* pt = (float*)d_ws;                         // nrows*64 fp32
  float* partial = pt + (size_t)nrows * 64;         // B fp32
  short* Wb = (short*)(partial + B);                // 64*D bf16

  conv_w<<<(64 * D + 255) / 256, 256, 0, stream>>>(W, Wb, V, D);

  dim3 g1((nrows + 63) / 64);                       // 4 waves x 16 rows
  gemm_pexp<<<g1, 256, 0, stream>>>(feat, Wb, bias, pt, nrows, D, V);

  star_dp<<<B, 64, 0, stream>>>(pt, targets, in_len, tgt_len, partial, T, S);

  reduce_mean<<<1, 64, 0, stream>>>(partial, out, B);
}

// Round 5
// 725.914 us; speedup vs baseline: 1.9948x; 1.2677x over previous
//
#include <hip/hip_runtime.h>
#include <hip/hip_bf16.h>
#include <math.h>

typedef __attribute__((ext_vector_type(4))) float f32x4;
typedef __attribute__((ext_vector_type(8))) short s16x8;

#define LOG2E 1.4426950408889634f
#define LN2f  0.6931471805599453f
#define INV_E 0.36787944117144233f

__device__ __forceinline__ short bfc(float x) {
  unsigned u = __float_as_uint(x);
  unsigned r = u + 0x7fffu + ((u >> 16) & 1u);   // RNE to bf16
  return (short)(r >> 16);
}

__device__ __forceinline__ unsigned pk2(float x, float y) {
  union { __hip_bfloat162 h; unsigned u; } c;
  c.h = __float22bfloat162_rn(make_float2(x, y));  // v_cvt_pk_bf16_f32
  return c.u;
}

__device__ __forceinline__ float bperm(float v, int byte_addr) {
  return __int_as_float(__builtin_amdgcn_ds_bpermute(byte_addr, __float_as_int(v)));
}

__device__ __forceinline__ float rdlane(float v, int lane) {
  return __int_as_float(__builtin_amdgcn_readlane(__float_as_int(v), lane));
}

// ---------------------------------------------------------------------------
// Kernel 0: W (V x D fp32) -> Wb (64 x D bf16), rows >= V zero-filled.
// ---------------------------------------------------------------------------
__global__ void conv_w(const float* __restrict__ W, short* __restrict__ Wb,
                       int V, int D) {
  int idx = blockIdx.x * blockDim.x + threadIdx.x;
  if (idx >= 64 * D) return;
  int row = idx / D, col = idx - row * D;
  Wb[idx] = (row < V) ? bfc(W[(size_t)row * D + col]) : (short)0;
}

// ---------------------------------------------------------------------------
// Kernel 1: per row: logits = feat @ W^T + b; m = rowmax; p~ = exp(logit-m)
// -> pt[row][0..55]; pt[row][56] = K = ln(sum p~); pt[row][57] = star~ =
// sum * e^-1; cols 58..63 = 0. bf16 MFMA 16x16x32, 16 rows/wave, no LDS.
// Packed v_cvt_pk_bf16_f32 conversion (4 insts vs ~40 scalar).
// ---------------------------------------------------------------------------
__global__ __launch_bounds__(256) void gemm_pexp(
    const float* __restrict__ feat, const short* __restrict__ Wb,
    const float* __restrict__ bias, float* __restrict__ pt,
    int nrows, int D, int V) {
  const int lane = threadIdx.x & 63;
  const int wave = threadIdx.x >> 6;
  const int m_lo = lane & 15;
  const int q = lane >> 4;
  const int rowbase = (blockIdx.x * 4 + wave) * 16;

  int arow = rowbase + m_lo;
  if (arow >= nrows) arow = nrows - 1;           // clamp loads; stores guarded
  const float* Ap = feat + (size_t)arow * D + q * 8;
  const short* Bp = Wb + (size_t)m_lo * D + q * 8;
  const size_t bstr = (size_t)16 * D;

  f32x4 acc[4];
  #pragma unroll
  for (int ni = 0; ni < 4; ++ni) acc[ni] = (f32x4){0.f, 0.f, 0.f, 0.f};

  float4 al = *(const float4*)(Ap);
  float4 ah = *(const float4*)(Ap + 4);
  s16x8 b0 = *(const s16x8*)(Bp);
  s16x8 b1 = *(const s16x8*)(Bp + bstr);
  s16x8 b2 = *(const s16x8*)(Bp + 2 * bstr);
  s16x8 b3 = *(const s16x8*)(Bp + 3 * bstr);

  for (int k0 = 0; k0 < D; k0 += 32) {
    const int kn = (k0 + 32 < D) ? (k0 + 32) : 0;  // dummy reload on last iter
    const float* Apn = feat + (size_t)arow * D + kn + q * 8;
    const short* Bpn = Wb + (size_t)m_lo * D + kn + q * 8;
    float4 nal = *(const float4*)(Apn);
    float4 nah = *(const float4*)(Apn + 4);
    s16x8 nb0 = *(const s16x8*)(Bpn);
    s16x8 nb1 = *(const s16x8*)(Bpn + bstr);
    s16x8 nb2 = *(const s16x8*)(Bpn + 2 * bstr);
    s16x8 nb3 = *(const s16x8*)(Bpn + 3 * bstr);

    union { s16x8 v; unsigned u[4]; } av;
    av.u[0] = pk2(al.x, al.y);
    av.u[1] = pk2(al.z, al.w);
    av.u[2] = pk2(ah.x, ah.y);
    av.u[3] = pk2(ah.z, ah.w);

    acc[0] = __builtin_amdgcn_mfma_f32_16x16x32_bf16(av.v, b0, acc[0], 0, 0, 0);
    acc[1] = __builtin_amdgcn_mfma_f32_16x16x32_bf16(av.v, b1, acc[1], 0, 0, 0);
    acc[2] = __builtin_amdgcn_mfma_f32_16x16x32_bf16(av.v, b2, acc[2], 0, 0, 0);
    acc[3] = __builtin_amdgcn_mfma_f32_16x16x32_bf16(av.v, b3, acc[3], 0, 0, 0);

    al = nal; ah = nah; b0 = nb0; b1 = nb1; b2 = nb2; b3 = nb3;
  }

  float bias_v[4];
  #pragma unroll
  for (int ni = 0; ni < 4; ++ni) {
    int col = ni * 16 + m_lo;
    bias_v[ni] = (col < V) ? bias[col] : 0.f;
  }

  // C/D layout: col = lane&15, row = (lane>>4)*4 + reg   [m89-verified]
  #pragma unroll
  for (int r = 0; r < 4; ++r) {
    int grow = rowbase + q * 4 + r;
    float lg[4];
    #pragma unroll
    for (int ni = 0; ni < 4; ++ni) {
      int col = ni * 16 + m_lo;
      lg[ni] = (col < V) ? (acc[ni][r] + bias_v[ni]) : -1e30f;
    }
    float m = fmaxf(fmaxf(lg[0], lg[1]), fmaxf(lg[2], lg[3]));
    #pragma unroll
    for (int off = 1; off < 16; off <<= 1) m = fmaxf(m, __shfl_xor(m, off));
    float p[4];
    #pragma unroll
    for (int ni = 0; ni < 4; ++ni) p[ni] = exp2f((lg[ni] - m) * LOG2E);
    float s = (p[0] + p[1]) + (p[2] + p[3]);
    #pragma unroll
    for (int off = 1; off < 16; off <<= 1) s += __shfl_xor(s, off);

    if (grow < nrows) {
      float* orow = pt + (size_t)grow * 64;
      orow[m_lo] = p[0];
      orow[16 + m_lo] = p[1];
      orow[32 + m_lo] = p[2];
      if (m_lo < 8)       orow[48 + m_lo] = p[3];
      else if (m_lo == 8) orow[56] = logf(s);        // K_t (ln units)
      else if (m_lo == 9) orow[57] = s * INV_E;      // star~ emission
      else                orow[48 + m_lo] = 0.f;     // cols 58..63
    }
  }
}

// ---------------------------------------------------------------------------
// Kernel 2: Star-CTC DP, linear domain, per-lane block-floating-point.
// v2: 8-deep register prefetch ring (8 global loads in flight), emissions
// software-pipelined one step ahead (bperm latency hidden), fast-path frame
// merge (scale incoming up when gap<=24; overflow-safe since renorm every 8
// steps bounds in-frame values by ~2^15, so <=2^79 worst-case transient).
// ---------------------------------------------------------------------------
__global__ __launch_bounds__(64) void star_dp(
    const float* __restrict__ pt, const int* __restrict__ targets,
    const int* __restrict__ in_len, const int* __restrict__ tgt_len,
    float* __restrict__ partial, int T, int S) {
  const int n = blockIdx.x;
  const int lane = threadIdx.x;
  const float* row = pt + (size_t)n * T * 64;
  const int len = in_len[n];
  const int tl = tgt_len[n];
  const int* tg = targets + (size_t)n * S;

  const int s0 = lane * 4;
  int lab1 = (s0     < S) ? tg[s0]     : 0;
  int lab3 = (s0 + 1 < S) ? tg[s0 + 1] : 0;
  int lab5 = (s0 + 2 < S) ? tg[s0 + 2] : 0;
  int lab7 = (s0 + 3 < S) ? tg[s0 + 3] : 0;
  int labL = __shfl_up(lab7, 1);                 // label of state 8k-1
  const bool sk1 = (lane > 0) && (lab1 != labL);
  const bool sk3 = (lab3 != lab1);
  const bool sk5 = (lab5 != lab3);
  const bool sk7 = (lab7 != lab5);
  const int ad1 = lab1 << 2, ad3 = lab3 << 2, ad5 = lab5 << 2, ad7 = lab7 << 2;

  float a0 = 0, a1 = 0, a2 = 0, a3 = 0, a4 = 0, a5 = 0, a6 = 0, a7 = 0, a8 = 0;
  int eps = 0;
  bool act = (lane == 0);

#define ROWL(t) row[(size_t)(((t) < len) ? (t) : (len - 1)) * 64 + lane]

  // t = 0
  float rc = row[lane];
  float es = rdlane(rc, 57);
  float e1v = bperm(rc, ad1), e3v, e5v, e7v;
  if (lane == 0) { a0 = es; a1 = e1v; }
  float ksum = rc;

  // prefetch ring: rr_j = row[1+j]
  float rr0 = ROWL(1), rr1 = ROWL(2), rr2 = ROWL(3), rr3 = ROWL(4);
  float rr4 = ROWL(5), rr5 = ROWL(6), rr6 = ROWL(7), rr7 = ROWL(8);

  // emissions for t = 1
  es = rdlane(rr0, 57);
  e1v = bperm(rr0, ad1); e3v = bperm(rr0, ad3);
  e5v = bperm(rr0, ad5); e7v = bperm(rr0, ad7);

  float l7 = __shfl_up(a7, 1);
  int eL = __shfl_up(eps, 1);

#define STEP(CUR, NXT, PFT, DOREN)                                           \
  do {                                                                       \
    ksum += CUR;                                                             \
    CUR = ROWL(PFT);                              /* refill ring slot */     \
    if (!act) eps = eL;                                                      \
    bool inc = (lane != 0) && (l7 != 0.f);                                   \
    int d = inc ? (eL - eps) : 0;                                            \
    float l7s;                                                               \
    if (__builtin_expect(d > 24, 0)) {            /* rare: raise own frame */\
      a0 = ldexpf(a0, -d); a1 = ldexpf(a1, -d); a2 = ldexpf(a2, -d);         \
      a3 = ldexpf(a3, -d); a4 = ldexpf(a4, -d); a5 = ldexpf(a5, -d);         \
      a6 = ldexpf(a6, -d); a7 = ldexpf(a7, -d); a8 = ldexpf(a8, -d);         \
      eps += d; l7s = l7;                                                    \
    } else {                                                                 \
      l7s = inc ? ldexpf(l7, d) : 0.f;            /* d<=24: safe scale-up */ \
    }                                                                        \
    act = act || (l7s != 0.f);                                               \
    float n7 = (a7 + a6 + (sk7 ? a5 : 0.f)) * e7v;                           \
    float n8 = (a8 + a7) * es;                                               \
    float n0 = (a0 + l7s) * es;                                              \
    float n1 = (a1 + a0 + (sk1 ? l7s : 0.f)) * e1v;                          \
    float n2 = (a2 + a1) * es;                                               \
    float n3 = (a3 + a2 + (sk3 ? a1 : 0.f)) * e3v;                           \
    float n4 = (a4 + a3) * es;                                               \
    float n5 = (a5 + a4 + (sk5 ? a3 : 0.f)) * e5v;                           \
    float n6 = (a6 + a5) * es;                                               \
    a0 = n0; a1 = n1; a2 = n2; a3 = n3; a4 = n4;                             \
    a5 = n5; a6 = n6; a7 = n7; a8 = n8;                                      \
    if (DOREN) {                                  /* per-lane renorm */      \
      float m = fmaxf(fmaxf(fmaxf(a0, a1), fmaxf(a2, a3)),                   \
                      fmaxf(fmaxf(a4, a5), fmaxf(a6, a7)));                  \
      m = fmaxf(m, a8);                                                      \
      int e = (int)((__float_as_uint(m) >> 23) & 255) - 126;                 \
      e = (act && m > 0.f) ? e : 0;                                          \
      a0 = ldexpf(a0, -e); a1 = ldexpf(a1, -e); a2 = ldexpf(a2, -e);         \
      a3 = ldexpf(a3, -e); a4 = ldexpf(a4, -e); a5 = ldexpf(a5, -e);         \
      a6 = ldexpf(a6, -e); a7 = ldexpf(a7, -e); a8 = ldexpf(a8, -e);         \
      eps += e;                                                              \
    }                                                                        \
    l7 = __shfl_up(a7, 1);                                                   \
    eL = __shfl_up(eps, 1);                                                  \
    es = rdlane(NXT, 57);                         /* gather for next step */ \
    e1v = bperm(NXT, ad1); e3v = bperm(NXT, ad3);                            \
    e5v = bperm(NXT, ad5); e7v = bperm(NXT, ad7);                            \
  } while (0)

  int t0 = 1;
  for (; t0 + 8 <= len; t0 += 8) {
    STEP(rr0, rr1, t0 + 8, false);
    STEP(rr1, rr2, t0 + 9, false);
    STEP(rr2, rr3, t0 + 10, false);
    STEP(rr3, rr4, t0 + 11, false);
    STEP(rr4, rr5, t0 + 12, false);
    STEP(rr5, rr6, t0 + 13, false);
    STEP(rr6, rr7, t0 + 14, false);
    STEP(rr7, rr0, t0 + 15, true);    // t = t0+7 == 0 (mod 8) -> renorm
  }

  // tail: <= 7 steps, unpipelined loads (emissions still pipelined)
  for (int t = t0; t < len; ++t) {
    float cur = ROWL(t);
    float nxt = ROWL(t + 1);
    ksum += cur;
    if (!act) eps = eL;
    bool inc = (lane != 0) && (l7 != 0.f);
    int d = inc ? (eL - eps) : 0;
    float l7s;
    if (__builtin_expect(d > 24, 0)) {
      a0 = ldexpf(a0, -d); a1 = ldexpf(a1, -d); a2 = ldexpf(a2, -d);
      a3 = ldexpf(a3, -d); a4 = ldexpf(a4, -d); a5 = ldexpf(a5, -d);
      a6 = ldexpf(a6, -d); a7 = ldexpf(a7, -d); a8 = ldexpf(a8, -d);
      eps += d; l7s = l7;
    } else {
      l7s = inc ? ldexpf(l7, d) : 0.f;
    }
    act = act || (l7s != 0.f);
    float n7 = (a7 + a6 + (sk7 ? a5 : 0.f)) * e7v;
    float n8 = (a8 + a7) * es;
    float n0 = (a0 + l7s) * es;
    float n1 = (a1 + a0 + (sk1 ? l7s : 0.f)) * e1v;
    float n2 = (a2 + a1) * es;
    float n3 = (a3 + a2 + (sk3 ? a1 : 0.f)) * e3v;
    float n4 = (a4 + a3) * es;
    float n5 = (a5 + a4 + (sk5 ? a3 : 0.f)) * e5v;
    float n6 = (a6 + a5) * es;
    a0 = n0; a1 = n1; a2 = n2; a3 = n3; a4 = n4;
    a5 = n5; a6 = n6; a7 = n7; a8 = n8;
    if ((t & 7) == 0) {
      float m = fmaxf(fmaxf(fmaxf(a0, a1), fmaxf(a2, a3)),
                      fmaxf(fmaxf(a4, a5), fmaxf(a6, a7)));
      m = fmaxf(m, a8);
      int e = (int)((__float_as_uint(m) >> 23) & 255) - 126;
      e = (act && m > 0.f) ? e : 0;
      a0 = ldexpf(a0, -e); a1 = ldexpf(a1, -e); a2 = ldexpf(a2, -e);
      a3 = ldexpf(a3, -e); a4 = ldexpf(a4, -e); a5 = ldexpf(a5, -e);
      a6 = ldexpf(a6, -e); a7 = ldexpf(a7, -e); a8 = ldexpf(a8, -e);
      eps += e;
    }
    l7 = __shfl_up(a7, 1);
    eL = __shfl_up(eps, 1);
    es = rdlane(nxt, 57);
    e1v = bperm(nxt, ad1); e3v = bperm(nxt, ad3);
    e5v = bperm(nxt, ad5); e7v = bperm(nxt, ad7);
  }

  __shared__ float sh[64 * 9];
  __shared__ int she[64];
  sh[lane * 9 + 0] = a0; sh[lane * 9 + 1] = a1; sh[lane * 9 + 2] = a2;
  sh[lane * 9 + 3] = a3; sh[lane * 9 + 4] = a4; sh[lane * 9 + 5] = a5;
  sh[lane * 9 + 6] = a6; sh[lane * 9 + 7] = a7; sh[lane * 9 + 8] = a8;
  she[lane] = eps;
  float k56 = __shfl(ksum, 56);
  __syncthreads();
  if (lane == 0) {
    int last = 2 * tl;
    int kx = last >> 3, jx = last & 7;
    if (kx > 63) { kx = 63; jx = last - 504; }     // state 512 -> lane63 a8
    int ky = (last - 1) >> 3, jy = (last - 1) & 7;
    float sx = sh[kx * 9 + jx]; int ex = she[kx];
    float sy = sh[ky * 9 + jy]; int ey = she[ky];
    int em = (ex > ey) ? ex : ey;
    float v = ldexpf(sx, ex - em) + ldexpf(sy, ey - em);
    float score = logf(v) + (float)em * LN2f - k56;
    partial[n] = -score / (float)tl;
  }
}

// ---------------------------------------------------------------------------
// Kernel 3: mean over batch
// ---------------------------------------------------------------------------
__global__ void reduce_mean(const float* __restrict__ partial,
                            float* __restrict__ out, int B) {
  float v = 0.f;
  for (int i = threadIdx.x; i < B; i += 64) v += partial[i];
  #pragma unroll
  for (int off = 32; off > 0; off >>= 1) v += __shfl_down(v, off, 64);
  if (threadIdx.x == 0) out[0] = v / (float)B;
}

extern "C" void kernel_launch(void* const* d_in, const int* in_sizes, int n_in,
                              void* d_out, int out_size, void* d_ws, size_t ws_size,
                              hipStream_t stream) {
  const float* feat = (const float*)d_in[0];
  const float* W = (const float*)d_in[1];
  const float* bias = (const float*)d_in[2];
  const int* targets = (const int*)d_in[3];
  const int* in_len = (const int*)d_in[4];
  const int* tgt_len = (const int*)d_in[5];
  float* out = (float*)d_out;

  const int V = in_sizes[2];
  const int D = in_sizes[1] / V;
  const int B = in_sizes[4];
  const int T = in_sizes[0] / (B * D);
  const int S = in_sizes[3] / B;
  const int nrows = B * T;

  float* pt = (float*)d_ws;                         // nrows*64 fp32
  float* partial = pt + (size_t)nrows * 64;         // B fp32
  short* Wb = (short*)(partial + B);                // 64*D bf16

  conv_w<<<(64 * D + 255) / 256, 256, 0, stream>>>(W, Wb, V, D);

  dim3 g1((nrows + 63) / 64);                       // 4 waves x 16 rows
  gemm_pexp<<<g1, 256, 0, stream>>>(feat, Wb, bias, pt, nrows, D, V);

  star_dp<<<B, 64, 0, stream>>>(pt, targets, in_len, tgt_len, partial, T, S);

  reduce_mean<<<1, 64, 0, stream>>>(partial, out, B);
}

// Round 6
// 723.963 us; speedup vs baseline: 2.0002x; 1.0027x over previous
//
#include <hip/hip_runtime.h>
#include <hip/hip_bf16.h>
#include <math.h>

typedef __attribute__((ext_vector_type(4))) float f32x4;
typedef __attribute__((ext_vector_type(8))) short s16x8;

#define LOG2E 1.4426950408889634f
#define LN2f  0.6931471805599453f
#define INV_E 0.36787944117144233f

__device__ __forceinline__ short bfc(float x) {
  unsigned u = __float_as_uint(x);
  unsigned r = u + 0x7fffu + ((u >> 16) & 1u);   // RNE to bf16
  return (short)(r >> 16);
}

__device__ __forceinline__ unsigned pk2(float x, float y) {
  union { __hip_bfloat162 h; unsigned u; } c;
  c.h = __float22bfloat162_rn(make_float2(x, y));  // v_cvt_pk_bf16_f32
  return c.u;
}

__device__ __forceinline__ float bperm(float v, int byte_addr) {
  return __int_as_float(__builtin_amdgcn_ds_bpermute(byte_addr, __float_as_int(v)));
}

__device__ __forceinline__ float rdlane(float v, int lane) {
  return __int_as_float(__builtin_amdgcn_readlane(__float_as_int(v), lane));
}

// ---------------------------------------------------------------------------
// Kernel 0: W (V x D fp32) -> Wb (64 x D bf16), rows >= V zero-filled.
// ---------------------------------------------------------------------------
__global__ void conv_w(const float* __restrict__ W, short* __restrict__ Wb,
                       int V, int D) {
  int idx = blockIdx.x * blockDim.x + threadIdx.x;
  if (idx >= 64 * D) return;
  int row = idx / D, col = idx - row * D;
  Wb[idx] = (row < V) ? bfc(W[(size_t)row * D + col]) : (short)0;
}

// ---------------------------------------------------------------------------
// Kernel 1: per row: logits = feat @ W^T + b; m = rowmax; p~ = exp(logit-m)
// -> pt[row][0..55]; pt[row][56] = K = ln(sum p~); pt[row][57] = star~ =
// sum * e^-1; cols 58..63 = 0. bf16 MFMA 16x16x32, 32 rows/wave (2 row
// groups x 4 col groups = 8 MFMA per 32-K iter), no LDS.
// ---------------------------------------------------------------------------
__global__ __launch_bounds__(256) void gemm_pexp(
    const float* __restrict__ feat, const short* __restrict__ Wb,
    const float* __restrict__ bias, float* __restrict__ pt,
    int nrows, int D, int V) {
  const int lane = threadIdx.x & 63;
  const int wave = threadIdx.x >> 6;
  const int m_lo = lane & 15;
  const int q = lane >> 4;
  const int rowbase = (blockIdx.x * 4 + wave) * 32;

  int arow0 = rowbase + m_lo;
  int arow1 = rowbase + 16 + m_lo;
  if (arow0 >= nrows) arow0 = nrows - 1;         // clamp loads; stores guarded
  if (arow1 >= nrows) arow1 = nrows - 1;
  const float* Ap0 = feat + (size_t)arow0 * D + q * 8;
  const float* Ap1 = feat + (size_t)arow1 * D + q * 8;
  const short* Bp = Wb + (size_t)m_lo * D + q * 8;
  const size_t bstr = (size_t)16 * D;

  f32x4 acc[2][4];
  #pragma unroll
  for (int g = 0; g < 2; ++g)
    #pragma unroll
    for (int ni = 0; ni < 4; ++ni) acc[g][ni] = (f32x4){0.f, 0.f, 0.f, 0.f};

  float4 al0 = *(const float4*)(Ap0);
  float4 ah0 = *(const float4*)(Ap0 + 4);
  float4 al1 = *(const float4*)(Ap1);
  float4 ah1 = *(const float4*)(Ap1 + 4);
  s16x8 b0 = *(const s16x8*)(Bp);
  s16x8 b1 = *(const s16x8*)(Bp + bstr);
  s16x8 b2 = *(const s16x8*)(Bp + 2 * bstr);
  s16x8 b3 = *(const s16x8*)(Bp + 3 * bstr);

  for (int k0 = 0; k0 < D; k0 += 32) {
    const int kn = (k0 + 32 < D) ? (k0 + 32) : 0;  // dummy reload on last iter
    const float* Ap0n = feat + (size_t)arow0 * D + kn + q * 8;
    const float* Ap1n = feat + (size_t)arow1 * D + kn + q * 8;
    const short* Bpn = Wb + (size_t)m_lo * D + kn + q * 8;
    float4 nal0 = *(const float4*)(Ap0n);
    float4 nah0 = *(const float4*)(Ap0n + 4);
    float4 nal1 = *(const float4*)(Ap1n);
    float4 nah1 = *(const float4*)(Ap1n + 4);
    s16x8 nb0 = *(const s16x8*)(Bpn);
    s16x8 nb1 = *(const s16x8*)(Bpn + bstr);
    s16x8 nb2 = *(const s16x8*)(Bpn + 2 * bstr);
    s16x8 nb3 = *(const s16x8*)(Bpn + 3 * bstr);

    union { s16x8 v; unsigned u[4]; } av0, av1;
    av0.u[0] = pk2(al0.x, al0.y); av0.u[1] = pk2(al0.z, al0.w);
    av0.u[2] = pk2(ah0.x, ah0.y); av0.u[3] = pk2(ah0.z, ah0.w);
    av1.u[0] = pk2(al1.x, al1.y); av1.u[1] = pk2(al1.z, al1.w);
    av1.u[2] = pk2(ah1.x, ah1.y); av1.u[3] = pk2(ah1.z, ah1.w);

    acc[0][0] = __builtin_amdgcn_mfma_f32_16x16x32_bf16(av0.v, b0, acc[0][0], 0, 0, 0);
    acc[0][1] = __builtin_amdgcn_mfma_f32_16x16x32_bf16(av0.v, b1, acc[0][1], 0, 0, 0);
    acc[0][2] = __builtin_amdgcn_mfma_f32_16x16x32_bf16(av0.v, b2, acc[0][2], 0, 0, 0);
    acc[0][3] = __builtin_amdgcn_mfma_f32_16x16x32_bf16(av0.v, b3, acc[0][3], 0, 0, 0);
    acc[1][0] = __builtin_amdgcn_mfma_f32_16x16x32_bf16(av1.v, b0, acc[1][0], 0, 0, 0);
    acc[1][1] = __builtin_amdgcn_mfma_f32_16x16x32_bf16(av1.v, b1, acc[1][1], 0, 0, 0);
    acc[1][2] = __builtin_amdgcn_mfma_f32_16x16x32_bf16(av1.v, b2, acc[1][2], 0, 0, 0);
    acc[1][3] = __builtin_amdgcn_mfma_f32_16x16x32_bf16(av1.v, b3, acc[1][3], 0, 0, 0);

    al0 = nal0; ah0 = nah0; al1 = nal1; ah1 = nah1;
    b0 = nb0; b1 = nb1; b2 = nb2; b3 = nb3;
  }

  float bias_v[4];
  #pragma unroll
  for (int ni = 0; ni < 4; ++ni) {
    int col = ni * 16 + m_lo;
    bias_v[ni] = (col < V) ? bias[col] : 0.f;
  }

  // C/D layout: col = lane&15, row = (lane>>4)*4 + reg   [m89-verified]
  #pragma unroll
  for (int g = 0; g < 2; ++g) {
    #pragma unroll
    for (int r = 0; r < 4; ++r) {
      int grow = rowbase + g * 16 + q * 4 + r;
      float lg[4];
      #pragma unroll
      for (int ni = 0; ni < 4; ++ni) {
        int col = ni * 16 + m_lo;
        lg[ni] = (col < V) ? (acc[g][ni][r] + bias_v[ni]) : -1e30f;
      }
      float m = fmaxf(fmaxf(lg[0], lg[1]), fmaxf(lg[2], lg[3]));
      #pragma unroll
      for (int off = 1; off < 16; off <<= 1) m = fmaxf(m, __shfl_xor(m, off));
      float p[4];
      #pragma unroll
      for (int ni = 0; ni < 4; ++ni) p[ni] = exp2f((lg[ni] - m) * LOG2E);
      float s = (p[0] + p[1]) + (p[2] + p[3]);
      #pragma unroll
      for (int off = 1; off < 16; off <<= 1) s += __shfl_xor(s, off);

      if (grow < nrows) {
        float* orow = pt + (size_t)grow * 64;
        orow[m_lo] = p[0];
        orow[16 + m_lo] = p[1];
        orow[32 + m_lo] = p[2];
        if (m_lo < 8)       orow[48 + m_lo] = p[3];
        else if (m_lo == 8) orow[56] = logf(s);        // K_t (ln units)
        else if (m_lo == 9) orow[57] = s * INV_E;      // star~ emission
        else                orow[48 + m_lo] = 0.f;     // cols 58..63
      }
    }
  }
}

// ---------------------------------------------------------------------------
// Kernel 2: Star-CTC DP, linear domain, per-lane block-floating-point, v3:
// 2-step time blocking. Boundary exchange (left a5,a6,a7 = states
// 8k-3..8k-1, + frame eps) once per PAIR of time steps -> one DS round-trip
// per 2 steps. Each lane redundantly advances boundary state 8k-1 (m1) for
// sub-step 1. Updates are in-place top-down (state i depends only on old
// states <= i). Gathers for the next pair are issued before the boundary
// shuffles so upper states of sub-step 1 can start on partial lgkmcnt.
// ---------------------------------------------------------------------------
__global__ __launch_bounds__(64) void star_dp(
    const float* __restrict__ pt, const int* __restrict__ targets,
    const int* __restrict__ in_len, const int* __restrict__ tgt_len,
    float* __restrict__ partial, int T, int S) {
  const int n = blockIdx.x;
  const int lane = threadIdx.x;
  const float* row = pt + (size_t)n * T * 64;
  const int len = in_len[n];
  const int tl = tgt_len[n];
  const int* tg = targets + (size_t)n * S;

  const int s0 = lane * 4;
  int lab1 = (s0     < S) ? tg[s0]     : 0;
  int lab3 = (s0 + 1 < S) ? tg[s0 + 1] : 0;
  int lab5 = (s0 + 2 < S) ? tg[s0 + 2] : 0;
  int lab7 = (s0 + 3 < S) ? tg[s0 + 3] : 0;
  int labm1 = __shfl_up(lab7, 1);                // label of state 8k-1
  int labm3 = __shfl_up(lab5, 1);                // label of state 8k-3
  const bool sk1 = (lane > 0) && (lab1 != labm1);
  const bool sk3 = (lab3 != lab1);
  const bool sk5 = (lab5 != lab3);
  const bool sk7 = (lab7 != lab5);
  const bool skm1 = (labm1 != labm3);
  const int ad1 = lab1 << 2, ad3 = lab3 << 2, ad5 = lab5 << 2, ad7 = lab7 << 2;
  const int adm1 = labm1 << 2;

  float a0 = 0, a1 = 0, a2 = 0, a3 = 0, a4 = 0, a5 = 0, a6 = 0, a7 = 0, a8 = 0;
  float m1 = 0.f, m2 = 0.f, m3 = 0.f;
  int eps = 0, eL = 0;
  bool act = (lane == 0);

#define ROWL(t) row[(size_t)(((t) < len) ? (t) : (len - 1)) * 64 + lane]

  // t = 0
  float rc = row[lane];
  {
    float star = rdlane(rc, 57);
    float e1i = bperm(rc, ad1);
    if (lane == 0) { a0 = star; a1 = e1i; }
  }
  float ksum = rc;

  // prefetch ring: rows 1..8
  float rr0 = ROWL(1), rr1 = ROWL(2), rr2 = ROWL(3), rr3 = ROWL(4);
  float rr4 = ROWL(5), rr5 = ROWL(6), rr6 = ROWL(7), rr7 = ROWL(8);

  // emissions for first pair (t=1,2)
  float es0v = rdlane(rr0, 57);
  float e1a = bperm(rr0, ad1), e3a = bperm(rr0, ad3);
  float e5a = bperm(rr0, ad5), e7a = bperm(rr0, ad7);
  float em1a = bperm(rr0, adm1);
  float es1v = rdlane(rr1, 57);
  float e1b = bperm(rr1, ad1), e3b = bperm(rr1, ad3);
  float e5b = bperm(rr1, ad5), e7b = bperm(rr1, ad7);

#define RENORM()                                                             \
  do {                                                                       \
    float mx = fmaxf(fmaxf(fmaxf(a0, a1), fmaxf(a2, a3)),                    \
                     fmaxf(fmaxf(a4, a5), fmaxf(a6, a7)));                   \
    mx = fmaxf(mx, a8);                                                      \
    int e = (int)((__float_as_uint(mx) >> 23) & 255) - 126;                  \
    e = (act && mx > 0.f) ? e : 0;                                           \
    a0 = ldexpf(a0, -e); a1 = ldexpf(a1, -e); a2 = ldexpf(a2, -e);           \
    a3 = ldexpf(a3, -e); a4 = ldexpf(a4, -e); a5 = ldexpf(a5, -e);           \
    a6 = ldexpf(a6, -e); a7 = ldexpf(a7, -e); a8 = ldexpf(a8, -e);           \
    eps += e;                                                                \
  } while (0)

#define PAIR(C0, C1, N0, N1, P0, P1, DOREN)                                  \
  do {                                                                       \
    ksum += C0; ksum += C1;                                                  \
    if (!act) eps = eL;                                                      \
    bool inc = (lane != 0) &&                                                \
               ((m1 != 0.f) || (m2 != 0.f) || (m3 != 0.f));                  \
    int d = inc ? (eL - eps) : 0;                                            \
    if (__builtin_expect(d > 24, 0)) {            /* raise own frame */      \
      a0 = ldexpf(a0, -d); a1 = ldexpf(a1, -d); a2 = ldexpf(a2, -d);         \
      a3 = ldexpf(a3, -d); a4 = ldexpf(a4, -d); a5 = ldexpf(a5, -d);         \
      a6 = ldexpf(a6, -d); a7 = ldexpf(a7, -d); a8 = ldexpf(a8, -d);         \
      eps += d;                                   /* m stay in frame eL */   \
    } else {                                                                 \
      m1 = ldexpf(m1, d); m2 = ldexpf(m2, d); m3 = ldexpf(m3, d);            \
    }                                                                        \
    act = act || (m1 != 0.f) || (m2 != 0.f) || (m3 != 0.f);                  \
    /* sub-step 1 (in-place top-down; uses old lower states) */              \
    a8 = (a8 + a7) * es0v;                                                   \
    a7 = (a7 + a6 + (sk7 ? a5 : 0.f)) * e7a;                                 \
    a6 = (a6 + a5) * es0v;                                                   \
    a5 = (a5 + a4 + (sk5 ? a3 : 0.f)) * e5a;                                 \
    a4 = (a4 + a3) * es0v;                                                   \
    a3 = (a3 + a2 + (sk3 ? a1 : 0.f)) * e3a;                                 \
    a2 = (a2 + a1) * es0v;                                                   \
    a1 = (a1 + a0 + (sk1 ? m1 : 0.f)) * e1a;                                 \
    a0 = (a0 + m1) * es0v;                                                   \
    m1 = (m1 + m2 + (skm1 ? m3 : 0.f)) * em1a;                               \
    /* sub-step 2 */                                                         \
    a8 = (a8 + a7) * es1v;                                                   \
    a7 = (a7 + a6 + (sk7 ? a5 : 0.f)) * e7b;                                 \
    a6 = (a6 + a5) * es1v;                                                   \
    a5 = (a5 + a4 + (sk5 ? a3 : 0.f)) * e5b;                                 \
    a4 = (a4 + a3) * es1v;                                                   \
    a3 = (a3 + a2 + (sk3 ? a1 : 0.f)) * e3b;                                 \
    a2 = (a2 + a1) * es1v;                                                   \
    a1 = (a1 + a0 + (sk1 ? m1 : 0.f)) * e1b;                                 \
    a0 = (a0 + m1) * es1v;                                                   \
    C0 = ROWL(P0); C1 = ROWL(P1);                 /* refill ring slots */    \
    if (DOREN) RENORM();                                                     \
    /* gathers for next pair FIRST (in-order DS: partial waits possible) */  \
    es0v = rdlane(N0, 57);                                                   \
    e1a = bperm(N0, ad1); e3a = bperm(N0, ad3);                              \
    e5a = bperm(N0, ad5); e7a = bperm(N0, ad7);                              \
    em1a = bperm(N0, adm1);                                                  \
    es1v = rdlane(N1, 57);                                                   \
    e1b = bperm(N1, ad1); e3b = bperm(N1, ad3);                              \
    e5b = bperm(N1, ad5); e7b = bperm(N1, ad7);                              \
    /* boundary shuffles (states 8k-3..8k-1 + frame) */                      \
    m3 = __shfl_up(a5, 1); m2 = __shfl_up(a6, 1); m1 = __shfl_up(a7, 1);     \
    eL = __shfl_up(eps, 1);                                                  \
    if (lane == 0) { m1 = 0.f; m2 = 0.f; m3 = 0.f; }                         \
  } while (0)

  int t0 = 1;
  for (; t0 + 8 <= len; t0 += 8) {
    PAIR(rr0, rr1, rr2, rr3, t0 + 8,  t0 + 9,  false);
    PAIR(rr2, rr3, rr4, rr5, t0 + 10, t0 + 11, false);
    PAIR(rr4, rr5, rr6, rr7, t0 + 12, t0 + 13, false);
    PAIR(rr6, rr7, rr0, rr1, t0 + 14, t0 + 15, true);  // t0+7 == 0 mod 8
  }

  // tail: <= 7 single steps (m1/eL re-shuffled each step)
  for (int t = t0; t < len; ++t) {
    float cur = ROWL(t);
    float esv = rdlane(cur, 57);
    float e1v = bperm(cur, ad1), e3v = bperm(cur, ad3);
    float e5v = bperm(cur, ad5), e7v = bperm(cur, ad7);
    ksum += cur;
    if (!act) eps = eL;
    bool inc = (lane != 0) && (m1 != 0.f);
    int d = inc ? (eL - eps) : 0;
    float m1s;
    if (__builtin_expect(d > 24, 0)) {
      a0 = ldexpf(a0, -d); a1 = ldexpf(a1, -d); a2 = ldexpf(a2, -d);
      a3 = ldexpf(a3, -d); a4 = ldexpf(a4, -d); a5 = ldexpf(a5, -d);
      a6 = ldexpf(a6, -d); a7 = ldexpf(a7, -d); a8 = ldexpf(a8, -d);
      eps += d; m1s = m1;
    } else {
      m1s = inc ? ldexpf(m1, d) : 0.f;
    }
    act = act || (m1s != 0.f);
    a8 = (a8 + a7) * esv;
    a7 = (a7 + a6 + (sk7 ? a5 : 0.f)) * e7v;
    a6 = (a6 + a5) * esv;
    a5 = (a5 + a4 + (sk5 ? a3 : 0.f)) * e5v;
    a4 = (a4 + a3) * esv;
    a3 = (a3 + a2 + (sk3 ? a1 : 0.f)) * e3v;
    a2 = (a2 + a1) * esv;
    a1 = (a1 + a0 + (sk1 ? m1s : 0.f)) * e1v;
    a0 = (a0 + m1s) * esv;
    if ((t & 7) == 0) RENORM();
    m1 = __shfl_up(a7, 1);
    eL = __shfl_up(eps, 1);
    if (lane == 0) m1 = 0.f;
  }

  __shared__ float sh[64 * 9];
  __shared__ int she[64];
  sh[lane * 9 + 0] = a0; sh[lane * 9 + 1] = a1; sh[lane * 9 + 2] = a2;
  sh[lane * 9 + 3] = a3; sh[lane * 9 + 4] = a4; sh[lane * 9 + 5] = a5;
  sh[lane * 9 + 6] = a6; sh[lane * 9 + 7] = a7; sh[lane * 9 + 8] = a8;
  she[lane] = eps;
  float k56 = __shfl(ksum, 56);
  __syncthreads();
  if (lane == 0) {
    int last = 2 * tl;
    int kx = last >> 3, jx = last & 7;
    if (kx > 63) { kx = 63; jx = last - 504; }     // state 512 -> lane63 a8
    int ky = (last - 1) >> 3, jy = (last - 1) & 7;
    float sx = sh[kx * 9 + jx]; int ex = she[kx];
    float sy = sh[ky * 9 + jy]; int ey = she[ky];
    int em = (ex > ey) ? ex : ey;
    float v = ldexpf(sx, ex - em) + ldexpf(sy, ey - em);
    float score = logf(v) + (float)em * LN2f - k56;
    partial[n] = -score / (float)tl;
  }
}

// ---------------------------------------------------------------------------
// Kernel 3: mean over batch
// ---------------------------------------------------------------------------
__global__ void reduce_mean(const float* __restrict__ partial,
                            float* __restrict__ out, int B) {
  float v = 0.f;
  for (int i = threadIdx.x; i < B; i += 64) v += partial[i];
  #pragma unroll
  for (int off = 32; off > 0; off >>= 1) v += __shfl_down(v, off, 64);
  if (threadIdx.x == 0) out[0] = v / (float)B;
}

extern "C" void kernel_launch(void* const* d_in, const int* in_sizes, int n_in,
                              void* d_out, int out_size, void* d_ws, size_t ws_size,
                              hipStream_t stream) {
  const float* feat = (const float*)d_in[0];
  const float* W = (const float*)d_in[1];
  const float* bias = (const float*)d_in[2];
  const int* targets = (const int*)d_in[3];
  const int* in_len = (const int*)d_in[4];
  const int* tgt_len = (const int*)d_in[5];
  float* out = (float*)d_out;

  const int V = in_sizes[2];
  const int D = in_sizes[1] / V;
  const int B = in_sizes[4];
  const int T = in_sizes[0] / (B * D);
  const int S = in_sizes[3] / B;
  const int nrows = B * T;

  float* pt = (float*)d_ws;                         // nrows*64 fp32
  float* partial = pt + (size_t)nrows * 64;         // B fp32
  short* Wb = (short*)(partial + B);                // 64*D bf16

  conv_w<<<(64 * D + 255) / 256, 256, 0, stream>>>(W, Wb, V, D);

  dim3 g1((nrows + 127) / 128);                     // 4 waves x 32 rows
  gemm_pexp<<<g1, 256, 0, stream>>>(feat, Wb, bias, pt, nrows, D, V);

  star_dp<<<B, 64, 0, stream>>>(pt, targets, in_len, tgt_len, partial, T, S);

  reduce_mean<<<1, 64, 0, stream>>>(partial, out, B);
}